// Round 1
// baseline (2749.528 us; speedup 1.0000x reference)
//
#include <hip/hip_runtime.h>

// Problem dims (fixed by reference)
#define NROWS  8192
#define INDIM  2048
#define LATDIM 16384
#define HIDDIM 2048
#define TOPK   32

// Ambiguity window: must be >= 2 * max bf16-GEMM latent error (8-sigma ~ 6e-3)
#define DELTA    0.012f
#define CAND_MAX 128

typedef __attribute__((ext_vector_type(8))) short bf16x8;
typedef __attribute__((ext_vector_type(4))) float f32x4;

// f32 -> bf16 round-to-nearest-even (bits)
__device__ __forceinline__ unsigned short f2bf(float f) {
  unsigned u = __float_as_uint(f);
  unsigned r = 0x7FFFu + ((u >> 16) & 1u);
  return (unsigned short)((u + r) >> 16);
}
// monotone float->uint key (ascending float => ascending uint)
__device__ __forceinline__ unsigned f2key(unsigned b) {
  return (b & 0x80000000u) ? ~b : (b | 0x80000000u);
}
__device__ __forceinline__ float key2f(unsigned k) {
  unsigned b = (k & 0x80000000u) ? (k ^ 0x80000000u) : ~k;
  return __uint_as_float(b);
}
// async global->LDS, 16B per lane; lds dest must be wave-uniform base (+lane*16)
__device__ __forceinline__ void gload16(const void* g, void* l) {
  __builtin_amdgcn_global_load_lds(
      (const __attribute__((address_space(1))) void*)g,
      (__attribute__((address_space(3))) void*)l, 16, 0, 0);
}

// ---------------- K1: x fp32 -> bf16 ----------------
__global__ __launch_bounds__(256)
void k_cvt_x(const float4* __restrict__ in, ushort4* __restrict__ out, int n4) {
  int i = blockIdx.x * 256 + threadIdx.x;
  if (i >= n4) return;
  float4 v = in[i];
  ushort4 o;
  o.x = f2bf(v.x); o.y = f2bf(v.y); o.z = f2bf(v.z); o.w = f2bf(v.w);
  out[i] = o;
}

// ---------------- K2: encoder [2048][16384] -> encT f32 [16384][2048] + encTb bf16 ----------------
__global__ __launch_bounds__(256)
void k_trans_enc(const float* __restrict__ enc,
                 float* __restrict__ encT,
                 unsigned short* __restrict__ encTb) {
  __shared__ float tile[32][33];
  const int c0 = blockIdx.x * 32;  // latent col base
  const int r0 = blockIdx.y * 32;  // input-dim row base
  const int tx = threadIdx.x, ty = threadIdx.y;
  #pragma unroll
  for (int i = ty; i < 32; i += 8)
    tile[i][tx] = enc[(size_t)(r0 + i) * LATDIM + c0 + tx];
  __syncthreads();
  #pragma unroll
  for (int i = ty; i < 32; i += 8) {
    float v = tile[tx][i];
    size_t o = (size_t)(c0 + i) * INDIM + r0 + tx;
    encT[o]  = v;
    encTb[o] = f2bf(v);
  }
}

// ---------------- K3: bf16 MFMA GEMM, m97 structure (128x128 tile, BK=64) ----------------
#define BM 128
#define BN 128
#define BK 64

__global__ __launch_bounds__(256)
void k_gemm(const unsigned short* __restrict__ A,   // xb   [NROWS][INDIM] bf16 bits
            const unsigned short* __restrict__ BT,  // encTb[LATDIM][INDIM] bf16 bits
            float* __restrict__ C)                  // latent [NROWS][LATDIM] f32
{
  __shared__ unsigned short Ash[BM * BK];  // [128][64] linear (global_load_lds needs linear)
  __shared__ unsigned short Bsh[BN * BK];
  const int tid  = threadIdx.x;
  const int lane = tid & 63, wid = tid >> 6;
  const int wr = wid >> 1, wc = wid & 1;          // 2x2 waves, 64x64 out each
  const int bx = blockIdx.x, by = blockIdx.y;

  const f32x4 fzero = {0.f, 0.f, 0.f, 0.f};
  f32x4 acc[4][4];
  #pragma unroll
  for (int m = 0; m < 4; ++m)
    #pragma unroll
    for (int n = 0; n < 4; ++n) acc[m][n] = fzero;

  // staging: chunk c (1024B = 8 rows of 64 bf16); lane covers row c*8+lane/8, k-offset (lane%8)*8
  const int rsub = lane >> 3;
  const int ksub = (lane & 7) * 8;
  const size_t aBase = (size_t)(by * BM) * INDIM;
  const size_t bBase = (size_t)(bx * BN) * INDIM;

  for (int k0 = 0; k0 < INDIM; k0 += BK) {
    #pragma unroll
    for (int j = 0; j < 4; ++j) {
      const int c = wid * 4 + j;                 // wave-uniform chunk id
      gload16(A  + aBase + (size_t)(c*8 + rsub) * INDIM + k0 + ksub, &Ash[c * 512]);
      gload16(BT + bBase + (size_t)(c*8 + rsub) * INDIM + k0 + ksub, &Bsh[c * 512]);
    }
    __syncthreads();   // compiler drains vmcnt(0) before barrier
    #pragma unroll
    for (int kk = 0; kk < 2; ++kk) {
      bf16x8 af[4], bfr[4];
      #pragma unroll
      for (int m = 0; m < 4; ++m)
        af[m]  = *(const bf16x8*)&Ash[(wr*64 + m*16 + (lane & 15)) * BK + kk*32 + (lane >> 4) * 8];
      #pragma unroll
      for (int n = 0; n < 4; ++n)
        bfr[n] = *(const bf16x8*)&Bsh[(wc*64 + n*16 + (lane & 15)) * BK + kk*32 + (lane >> 4) * 8];
      #pragma unroll
      for (int m = 0; m < 4; ++m)
        #pragma unroll
        for (int n = 0; n < 4; ++n)
          acc[m][n] = __builtin_amdgcn_mfma_f32_16x16x32_bf16(af[m], bfr[n], acc[m][n], 0, 0, 0);
    }
    __syncthreads();   // all waves done reading LDS before next stage overwrites
  }

  // C/D layout (m89-verified): col = lane&15, row = (lane>>4)*4 + reg
  const int r0  = by * BM + wr * 64;
  const int c0g = bx * BN + wc * 64;
  const int cr  = (lane >> 4) * 4;
  const int cc  = lane & 15;
  #pragma unroll
  for (int m = 0; m < 4; ++m)
    #pragma unroll
    for (int n = 0; n < 4; ++n)
      #pragma unroll
      for (int i = 0; i < 4; ++i)
        C[(size_t)(r0 + m*16 + cr + i) * LATDIM + c0g + n*16 + cc] = acc[m][n][i];
}

// ---------------- K4: exact top-32 select + boundary fp32 recompute + sparse rewrite ----------------
__global__ __launch_bounds__(256)
void k_topk(float* __restrict__ latent_sparse,   // d_out sparse region: latent in, sparse out
            const float* __restrict__ x,         // exact fp32 x
            const float* __restrict__ encT,      // exact fp32 encoder^T [LATDIM][INDIM]
            int* __restrict__ gIdx, float* __restrict__ gVal) {
  extern __shared__ unsigned int keys[];         // 64 KB dynamic
  __shared__ unsigned int hist[256];
  __shared__ int   selIdx[TOPK];
  __shared__ float selVal[TOPK];
  __shared__ int   candIdx[CAND_MAX];
  __shared__ float candApp[CAND_MAX];
  __shared__ float candEx[CAND_MAX];
  __shared__ unsigned char candUsed[CAND_MAX];
  __shared__ int nSel, nCand;
  __shared__ int sChosen, sNeed;

  const int tid = threadIdx.x;
  const int row = blockIdx.x;
  float* lrow = latent_sparse + (size_t)row * LATDIM;

  // 1. load row -> monotone keys in LDS
  const uint4* l4 = (const uint4*)lrow;
  for (int i = tid; i < LATDIM / 4; i += 256) {
    uint4 u = l4[i];
    keys[i*4+0] = f2key(u.x);
    keys[i*4+1] = f2key(u.y);
    keys[i*4+2] = f2key(u.z);
    keys[i*4+3] = f2key(u.w);
  }
  if (tid == 0) { nSel = 0; nCand = 0; }
  if (tid < TOPK) { selIdx[tid] = 0; selVal[tid] = 0.f; }
  __syncthreads();

  // 2. radix-select the exact 32nd-largest key (4 x 8-bit passes)
  unsigned prefix = 0; int need = TOPK;
  for (int pass = 0; pass < 4; ++pass) {
    const int shift = 24 - 8 * pass;
    hist[tid] = 0;
    __syncthreads();
    const unsigned maskAbove = (pass == 0) ? 0u : (0xFFFFFFFFu << (shift + 8));
    for (int i = tid; i < LATDIM; i += 256) {
      unsigned k = keys[i];
      if ((k & maskAbove) == prefix)
        atomicAdd(&hist[(k >> shift) & 0xFFu], 1u);
    }
    __syncthreads();
    if (tid == 0) {
      unsigned cum = 0; int chosen = 0; int nn = 1;
      for (int b = 255; b >= 0; --b) {
        unsigned c2 = cum + hist[b];
        if (c2 >= (unsigned)need) { chosen = b; nn = need - (int)cum; break; }
        cum = c2;
      }
      sChosen = chosen; sNeed = nn;
    }
    __syncthreads();
    prefix |= ((unsigned)sChosen << shift);
    need = sNeed;
    __syncthreads();
  }

  const float v32 = key2f(prefix);      // approx 32nd-largest value (exact among approx)
  const float thi = v32 + DELTA;
  const float tlo = v32 - DELTA;

  // 3. window scan: certain members (> thi, provably <= 31 of them) + ambiguous candidates
  for (int i = tid; i < LATDIM; i += 256) {
    float f = key2f(keys[i]);
    if (f > thi) {
      int p = atomicAdd(&nSel, 1);
      if (p < TOPK) { selIdx[p] = i; selVal[p] = f; }
    } else if (f >= tlo) {
      int p = atomicAdd(&nCand, 1);
      if (p < CAND_MAX) { candIdx[p] = i; candApp[p] = f; }
    }
  }
  __syncthreads();

  // 4. exact fp32 recompute of candidates (one wave per candidate)
  const int nc = min(nCand, CAND_MAX);
  const int lane = tid & 63, wid = tid >> 6;
  const float* xr = x + (size_t)row * INDIM;
  for (int c = wid; c < nc; c += 4) {
    const float* er = encT + (size_t)candIdx[c] * INDIM;
    float acc = 0.f;
    for (int k = lane; k < INDIM; k += 64)
      acc = fmaf(xr[k], er[k], acc);
    #pragma unroll
    for (int m2 = 32; m2 >= 1; m2 >>= 1)
      acc += __shfl_xor(acc, m2, 64);
    if (lane == 0) candEx[c] = acc;
  }
  __syncthreads();

  // 5. resolve membership among candidates by exact value (ties -> lower index, matches top_k)
  if (tid == 0) {
    int ns = min(nSel, TOPK);
    int needF = TOPK - ns;
    for (int c = 0; c < nc; ++c) candUsed[c] = 0;
    int filled = 0;
    for (int t = 0; t < needF; ++t) {
      int best = -1;
      for (int c = 0; c < nc; ++c) {
        if (candUsed[c]) continue;
        if (best < 0 || candEx[c] > candEx[best] ||
            (candEx[c] == candEx[best] && candIdx[c] < candIdx[best]))
          best = c;
      }
      if (best < 0) break;
      candUsed[best] = 1;
      selIdx[ns + filled] = candIdx[best];
      selVal[ns + filled] = candApp[best];
      ++filled;
    }
  }
  __syncthreads();

  // 6. emit lists + rewrite the row in-place as sparse (zeros + 32 scatter)
  if (tid < TOPK) {
    gIdx[(size_t)row * TOPK + tid] = selIdx[tid];
    gVal[(size_t)row * TOPK + tid] = selVal[tid];
  }
  const float4 z = {0.f, 0.f, 0.f, 0.f};
  float4* s4 = (float4*)lrow;
  for (int i = tid; i < LATDIM / 4; i += 256) s4[i] = z;
  __syncthreads();
  if (tid < TOPK) lrow[selIdx[tid]] = selVal[tid];
}

// ---------------- K5: decode (32 AXPYs of decoder rows per x-row) ----------------
__global__ __launch_bounds__(256)
void k_decode(const int* __restrict__ gIdx, const float* __restrict__ gVal,
              const float* __restrict__ dec, float* __restrict__ recon) {
  __shared__ int   sidx[TOPK];
  __shared__ float sval[TOPK];
  const int tid = threadIdx.x, row = blockIdx.x;
  if (tid < TOPK) {
    sidx[tid] = gIdx[(size_t)row * TOPK + tid];
    sval[tid] = gVal[(size_t)row * TOPK + tid];
  }
  __syncthreads();
  float4 a0 = {0.f,0.f,0.f,0.f}, a1 = {0.f,0.f,0.f,0.f};
  #pragma unroll 4
  for (int k = 0; k < TOPK; ++k) {
    const float v = sval[k];
    const float4* dr = (const float4*)(dec + (size_t)sidx[k] * HIDDIM);
    float4 d0 = dr[tid], d1 = dr[tid + 256];
    a0.x = fmaf(v, d0.x, a0.x); a0.y = fmaf(v, d0.y, a0.y);
    a0.z = fmaf(v, d0.z, a0.z); a0.w = fmaf(v, d0.w, a0.w);
    a1.x = fmaf(v, d1.x, a1.x); a1.y = fmaf(v, d1.y, a1.y);
    a1.z = fmaf(v, d1.z, a1.z); a1.w = fmaf(v, d1.w, a1.w);
  }
  float4* orow = (float4*)(recon + (size_t)row * HIDDIM);
  orow[tid] = a0; orow[tid + 256] = a1;
}

extern "C" void kernel_launch(void* const* d_in, const int* in_sizes, int n_in,
                              void* d_out, int out_size, void* d_ws, size_t ws_size,
                              hipStream_t stream) {
  (void)in_sizes; (void)n_in; (void)out_size; (void)ws_size;
  const float* x   = (const float*)d_in[0];   // [8192][2048]
  const float* enc = (const float*)d_in[1];   // [2048][16384]
  const float* dec = (const float*)d_in[2];   // [16384][2048]

  float* recon  = (float*)d_out;                        // [8192][2048]
  float* sparse = recon + (size_t)NROWS * HIDDIM;       // [8192][16384] (also latent scratch)

  // ws layout (~226 MB needed)
  char* w = (char*)d_ws;
  unsigned short* xb    = (unsigned short*)w;                             // 32 MB
  unsigned short* encTb = (unsigned short*)(w + (size_t)33554432);        // 64 MB
  float*          encT  = (float*)(w + (size_t)100663296);                // 128 MB
  int*            gIdx  = (int*)(w + (size_t)234881024);                  // 1 MB
  float*          gVal  = (float*)(w + (size_t)235929600);                // 1 MB

  k_cvt_x<<<(NROWS * INDIM / 4 + 255) / 256, 256, 0, stream>>>(
      (const float4*)x, (ushort4*)xb, NROWS * INDIM / 4);
  k_trans_enc<<<dim3(LATDIM / 32, INDIM / 32), dim3(32, 8), 0, stream>>>(enc, encT, encTb);
  k_gemm<<<dim3(LATDIM / BN, NROWS / BM), 256, 0, stream>>>(xb, encTb, sparse);
  k_topk<<<NROWS, 256, 65536, stream>>>(sparse, x, encT, gIdx, gVal);
  k_decode<<<NROWS, 256, 0, stream>>>(gIdx, gVal, dec, recon);
}

// Round 2
// 1849.752 us; speedup vs baseline: 1.4864x; 1.4864x over previous
//
#include <hip/hip_runtime.h>

// Problem dims (fixed by reference)
#define NROWS  8192
#define INDIM  2048
#define LATDIM 16384
#define HIDDIM 2048
#define TOPK   32

// Ambiguity window: must be >= 2 * max bf16-GEMM latent error (8-sigma ~ 6e-3)
#define DELTA    0.012f
#define CAND_MAX 128
#define BIS_ITERS 16

typedef __attribute__((ext_vector_type(8))) short bf16x8;
typedef __attribute__((ext_vector_type(4))) float f32x4;

// f32 -> bf16 round-to-nearest-even (bits)
__device__ __forceinline__ unsigned short f2bf(float f) {
  unsigned u = __float_as_uint(f);
  unsigned r = 0x7FFFu + ((u >> 16) & 1u);
  return (unsigned short)((u + r) >> 16);
}
// async global->LDS, 16B per lane; lds dest must be wave-uniform base (+lane*16)
__device__ __forceinline__ void gload16(const void* g, void* l) {
  __builtin_amdgcn_global_load_lds(
      (const __attribute__((address_space(1))) void*)g,
      (__attribute__((address_space(3))) void*)l, 16, 0, 0);
}

// ---------------- K1: x fp32 -> bf16 ----------------
__global__ __launch_bounds__(256)
void k_cvt_x(const float4* __restrict__ in, ushort4* __restrict__ out, int n4) {
  int i = blockIdx.x * 256 + threadIdx.x;
  if (i >= n4) return;
  float4 v = in[i];
  ushort4 o;
  o.x = f2bf(v.x); o.y = f2bf(v.y); o.z = f2bf(v.z); o.w = f2bf(v.w);
  out[i] = o;
}

// ---------------- K2: encoder [2048][16384] -> encT f32 [16384][2048] + encTb bf16 ----------------
__global__ __launch_bounds__(256)
void k_trans_enc(const float* __restrict__ enc,
                 float* __restrict__ encT,
                 unsigned short* __restrict__ encTb) {
  __shared__ float tile[32][33];
  const int c0 = blockIdx.x * 32;  // latent col base
  const int r0 = blockIdx.y * 32;  // input-dim row base
  const int tx = threadIdx.x, ty = threadIdx.y;
  #pragma unroll
  for (int i = ty; i < 32; i += 8)
    tile[i][tx] = enc[(size_t)(r0 + i) * LATDIM + c0 + tx];
  __syncthreads();
  #pragma unroll
  for (int i = ty; i < 32; i += 8) {
    float v = tile[tx][i];
    size_t o = (size_t)(c0 + i) * INDIM + r0 + tx;
    encT[o]  = v;
    encTb[o] = f2bf(v);
  }
}

// ---------------- K3: bf16 MFMA GEMM, m97 structure (128x128 tile, BK=64) ----------------
#define BM 128
#define BN 128
#define BK 64

__global__ __launch_bounds__(256)
void k_gemm(const unsigned short* __restrict__ A,   // xb   [NROWS][INDIM] bf16 bits
            const unsigned short* __restrict__ BT,  // encTb[LATDIM][INDIM] bf16 bits
            float* __restrict__ C)                  // latent [NROWS][LATDIM] f32
{
  __shared__ unsigned short Ash[BM * BK];  // [128][64] linear (global_load_lds needs linear)
  __shared__ unsigned short Bsh[BN * BK];
  const int tid  = threadIdx.x;
  const int lane = tid & 63, wid = tid >> 6;
  const int wr = wid >> 1, wc = wid & 1;          // 2x2 waves, 64x64 out each
  const int bx = blockIdx.x, by = blockIdx.y;

  const f32x4 fzero = {0.f, 0.f, 0.f, 0.f};
  f32x4 acc[4][4];
  #pragma unroll
  for (int m = 0; m < 4; ++m)
    #pragma unroll
    for (int n = 0; n < 4; ++n) acc[m][n] = fzero;

  // staging: chunk c (1024B = 8 rows of 64 bf16); lane covers row c*8+lane/8, k-offset (lane%8)*8
  const int rsub = lane >> 3;
  const int ksub = (lane & 7) * 8;
  const size_t aBase = (size_t)(by * BM) * INDIM;
  const size_t bBase = (size_t)(bx * BN) * INDIM;

  for (int k0 = 0; k0 < INDIM; k0 += BK) {
    #pragma unroll
    for (int j = 0; j < 4; ++j) {
      const int c = wid * 4 + j;                 // wave-uniform chunk id
      gload16(A  + aBase + (size_t)(c*8 + rsub) * INDIM + k0 + ksub, &Ash[c * 512]);
      gload16(BT + bBase + (size_t)(c*8 + rsub) * INDIM + k0 + ksub, &Bsh[c * 512]);
    }
    __syncthreads();   // compiler drains vmcnt(0) before barrier
    #pragma unroll
    for (int kk = 0; kk < 2; ++kk) {
      bf16x8 af[4], bfr[4];
      #pragma unroll
      for (int m = 0; m < 4; ++m)
        af[m]  = *(const bf16x8*)&Ash[(wr*64 + m*16 + (lane & 15)) * BK + kk*32 + (lane >> 4) * 8];
      #pragma unroll
      for (int n = 0; n < 4; ++n)
        bfr[n] = *(const bf16x8*)&Bsh[(wc*64 + n*16 + (lane & 15)) * BK + kk*32 + (lane >> 4) * 8];
      #pragma unroll
      for (int m = 0; m < 4; ++m)
        #pragma unroll
        for (int n = 0; n < 4; ++n)
          acc[m][n] = __builtin_amdgcn_mfma_f32_16x16x32_bf16(af[m], bfr[n], acc[m][n], 0, 0, 0);
    }
    __syncthreads();   // all waves done reading LDS before next stage overwrites
  }

  // C/D layout (m89-verified): col = lane&15, row = (lane>>4)*4 + reg
  const int r0  = by * BM + wr * 64;
  const int c0g = bx * BN + wc * 64;
  const int cr  = (lane >> 4) * 4;
  const int cc  = lane & 15;
  #pragma unroll
  for (int m = 0; m < 4; ++m)
    #pragma unroll
    for (int n = 0; n < 4; ++n)
      #pragma unroll
      for (int i = 0; i < 4; ++i)
        C[(size_t)(r0 + m*16 + cr + i) * LATDIM + c0g + n*16 + cc] = acc[m][n][i];
}

// ---------------- K4: exact top-32 via register-resident bisection ----------------
// One row per 256-thread block. Row lives in registers (64 floats/thread).
// Bisection on value domain finds [lo,hi] with cnt(>hi) <= 32 <= cnt(>lo).
// certain = approx > hi+DELTA (provable members); candidates in (lo-DELTA, hi+DELTA]
// get exact fp32 recompute. No big LDS, no histogram atomics.
__global__ __launch_bounds__(256)
void k_topk(float* __restrict__ latent_sparse,   // d_out sparse region: latent in, sparse out
            const float* __restrict__ x,         // exact fp32 x
            const float* __restrict__ encT,      // exact fp32 encoder^T [LATDIM][INDIM]
            int* __restrict__ gIdx, float* __restrict__ gVal) {
  __shared__ int   redi[2][4];                   // per-wave counts, double-buffered
  __shared__ float redf[8];                      // min/max partials
  __shared__ int   selIdx[TOPK];
  __shared__ float selVal[TOPK];
  __shared__ int   candIdx[CAND_MAX];
  __shared__ float candApp[CAND_MAX];
  __shared__ float candEx[CAND_MAX];
  __shared__ unsigned char candUsed[CAND_MAX];
  __shared__ int nSel, nCand;

  const int tid = threadIdx.x;
  const int lane = tid & 63, wid = tid >> 6;
  const int row = blockIdx.x;
  float* lrow = latent_sparse + (size_t)row * LATDIM;

  // 1. stream row into registers: v[i] = lrow4[i*256 + tid]
  float4 v[16];
  {
    const float4* l4 = (const float4*)lrow;
    #pragma unroll
    for (int i = 0; i < 16; ++i) v[i] = l4[i * 256 + tid];
  }
  if (tid == 0) { nSel = 0; nCand = 0; }
  if (tid < TOPK) { selIdx[tid] = 0; selVal[tid] = 0.f; }

  // 2. block min/max
  float mx = -1e30f, mn = 1e30f;
  #pragma unroll
  for (int i = 0; i < 16; ++i) {
    mx = fmaxf(mx, fmaxf(fmaxf(v[i].x, v[i].y), fmaxf(v[i].z, v[i].w)));
    mn = fminf(mn, fminf(fminf(v[i].x, v[i].y), fminf(v[i].z, v[i].w)));
  }
  #pragma unroll
  for (int m2 = 32; m2 >= 1; m2 >>= 1) {
    mx = fmaxf(mx, __shfl_xor(mx, m2, 64));
    mn = fminf(mn, __shfl_xor(mn, m2, 64));
  }
  if (lane == 0) { redf[wid] = mx; redf[4 + wid] = mn; }
  __syncthreads();
  mx = fmaxf(fmaxf(redf[0], redf[1]), fmaxf(redf[2], redf[3]));
  mn = fminf(fminf(redf[4], redf[5]), fminf(redf[6], redf[7]));

  // 3. bisection: invariant cnt(>lo) >= 32, cnt(>hi) <= 32
  float lo = mn - 1.0f, hi = mx;
  for (int it = 0; it < BIS_ITERS; ++it) {
    const float mid = 0.5f * (lo + hi);
    int c = 0;
    #pragma unroll
    for (int i = 0; i < 16; ++i) {
      c += __popcll(__ballot(v[i].x > mid));
      c += __popcll(__ballot(v[i].y > mid));
      c += __popcll(__ballot(v[i].z > mid));
      c += __popcll(__ballot(v[i].w > mid));
    }
    if (lane == 0) redi[it & 1][wid] = c;
    __syncthreads();
    const int total = redi[it & 1][0] + redi[it & 1][1] + redi[it & 1][2] + redi[it & 1][3];
    if (total >= TOPK) lo = mid; else hi = mid;   // wave-uniform, all threads agree
  }

  // 4. classify: certain members and ambiguous candidates
  const float chi = hi + DELTA;
  const float clo = lo - DELTA;
  #pragma unroll
  for (int i = 0; i < 16; ++i) {
    #pragma unroll
    for (int j = 0; j < 4; ++j) {
      const float f = (j == 0) ? v[i].x : (j == 1) ? v[i].y : (j == 2) ? v[i].z : v[i].w;
      const int idx = i * 1024 + tid * 4 + j;
      if (f > chi) {
        int p = atomicAdd(&nSel, 1);
        if (p < TOPK) { selIdx[p] = idx; selVal[p] = f; }
      } else if (f > clo) {
        int p = atomicAdd(&nCand, 1);
        if (p < CAND_MAX) { candIdx[p] = idx; candApp[p] = f; }
      }
    }
  }
  __syncthreads();

  // 5. exact fp32 recompute of candidates (one wave per candidate)
  const int nc = min(nCand, CAND_MAX);
  const float* xr = x + (size_t)row * INDIM;
  for (int c = wid; c < nc; c += 4) {
    const float* er = encT + (size_t)candIdx[c] * INDIM;
    float acc = 0.f;
    for (int k = lane; k < INDIM; k += 64)
      acc = fmaf(xr[k], er[k], acc);
    #pragma unroll
    for (int m2 = 32; m2 >= 1; m2 >>= 1)
      acc += __shfl_xor(acc, m2, 64);
    if (lane == 0) candEx[c] = acc;
  }
  __syncthreads();

  // 6. resolve membership among candidates by exact value (ties -> lower index)
  if (tid == 0) {
    int ns = min(nSel, TOPK);
    int needF = TOPK - ns;
    for (int c = 0; c < nc; ++c) candUsed[c] = 0;
    int filled = 0;
    for (int t = 0; t < needF; ++t) {
      int best = -1;
      for (int c = 0; c < nc; ++c) {
        if (candUsed[c]) continue;
        if (best < 0 || candEx[c] > candEx[best] ||
            (candEx[c] == candEx[best] && candIdx[c] < candIdx[best]))
          best = c;
      }
      if (best < 0) break;
      candUsed[best] = 1;
      selIdx[ns + filled] = candIdx[best];
      selVal[ns + filled] = candApp[best];
      ++filled;
    }
  }
  __syncthreads();

  // 7. emit lists + rewrite the row in-place as sparse (zeros + 32 scatter)
  if (tid < TOPK) {
    gIdx[(size_t)row * TOPK + tid] = selIdx[tid];
    gVal[(size_t)row * TOPK + tid] = selVal[tid];
  }
  {
    const float4 z = {0.f, 0.f, 0.f, 0.f};
    float4* s4 = (float4*)lrow;
    #pragma unroll
    for (int i = 0; i < 16; ++i) s4[i * 256 + tid] = z;
  }
  __syncthreads();
  if (tid < TOPK) lrow[selIdx[tid]] = selVal[tid];
}

// ---------------- K5: decode (32 AXPYs of decoder rows per x-row) ----------------
__global__ __launch_bounds__(256)
void k_decode(const int* __restrict__ gIdx, const float* __restrict__ gVal,
              const float* __restrict__ dec, float* __restrict__ recon) {
  __shared__ int   sidx[TOPK];
  __shared__ float sval[TOPK];
  const int tid = threadIdx.x, row = blockIdx.x;
  if (tid < TOPK) {
    sidx[tid] = gIdx[(size_t)row * TOPK + tid];
    sval[tid] = gVal[(size_t)row * TOPK + tid];
  }
  __syncthreads();
  float4 a0 = {0.f,0.f,0.f,0.f}, a1 = {0.f,0.f,0.f,0.f};
  #pragma unroll 4
  for (int k = 0; k < TOPK; ++k) {
    const float v = sval[k];
    const float4* dr = (const float4*)(dec + (size_t)sidx[k] * HIDDIM);
    float4 d0 = dr[tid], d1 = dr[tid + 256];
    a0.x = fmaf(v, d0.x, a0.x); a0.y = fmaf(v, d0.y, a0.y);
    a0.z = fmaf(v, d0.z, a0.z); a0.w = fmaf(v, d0.w, a0.w);
    a1.x = fmaf(v, d1.x, a1.x); a1.y = fmaf(v, d1.y, a1.y);
    a1.z = fmaf(v, d1.z, a1.z); a1.w = fmaf(v, d1.w, a1.w);
  }
  float4* orow = (float4*)(recon + (size_t)row * HIDDIM);
  orow[tid] = a0; orow[tid + 256] = a1;
}

extern "C" void kernel_launch(void* const* d_in, const int* in_sizes, int n_in,
                              void* d_out, int out_size, void* d_ws, size_t ws_size,
                              hipStream_t stream) {
  (void)in_sizes; (void)n_in; (void)out_size; (void)ws_size;
  const float* x   = (const float*)d_in[0];   // [8192][2048]
  const float* enc = (const float*)d_in[1];   // [2048][16384]
  const float* dec = (const float*)d_in[2];   // [16384][2048]

  float* recon  = (float*)d_out;                        // [8192][2048]
  float* sparse = recon + (size_t)NROWS * HIDDIM;       // [8192][16384] (also latent scratch)

  // ws layout (~226 MB needed)
  char* w = (char*)d_ws;
  unsigned short* xb    = (unsigned short*)w;                             // 32 MB
  unsigned short* encTb = (unsigned short*)(w + (size_t)33554432);        // 64 MB
  float*          encT  = (float*)(w + (size_t)100663296);                // 128 MB
  int*            gIdx  = (int*)(w + (size_t)234881024);                  // 1 MB
  float*          gVal  = (float*)(w + (size_t)235929600);                // 1 MB

  k_cvt_x<<<(NROWS * INDIM / 4 + 255) / 256, 256, 0, stream>>>(
      (const float4*)x, (ushort4*)xb, NROWS * INDIM / 4);
  k_trans_enc<<<dim3(LATDIM / 32, INDIM / 32), dim3(32, 8), 0, stream>>>(enc, encT, encTb);
  k_gemm<<<dim3(LATDIM / BN, NROWS / BM), 256, 0, stream>>>(xb, encTb, sparse);
  k_topk<<<NROWS, 256, 0, stream>>>(sparse, x, encT, gIdx, gVal);
  k_decode<<<NROWS, 256, 0, stream>>>(gIdx, gVal, dec, recon);
}

// Round 3
// 1528.066 us; speedup vs baseline: 1.7994x; 1.2105x over previous
//
#include <hip/hip_runtime.h>

// Problem dims (fixed by reference)
#define NROWS  8192
#define INDIM  2048
#define LATDIM 16384
#define HIDDIM 2048
#define TOPK   32

// Ambiguity window: must be >= 2 * max bf16-GEMM latent error (8-sigma ~ 6e-3)
#define DELTA    0.012f
#define CAND_MAX 128
#define BIS_ITERS 16

typedef __attribute__((ext_vector_type(8))) short bf16x8;
typedef __attribute__((ext_vector_type(4))) float f32x4;

// f32 -> bf16 round-to-nearest-even (bits)
__device__ __forceinline__ unsigned short f2bf(float f) {
  unsigned u = __float_as_uint(f);
  unsigned r = 0x7FFFu + ((u >> 16) & 1u);
  return (unsigned short)((u + r) >> 16);
}
// async global->LDS, 16B per lane; lds dest must be wave-uniform base (+lane*16)
__device__ __forceinline__ void gload16(const void* g, void* l) {
  __builtin_amdgcn_global_load_lds(
      (const __attribute__((address_space(1))) void*)g,
      (__attribute__((address_space(3))) void*)l, 16, 0, 0);
}

// ---------------- K1: x fp32 -> bf16 ----------------
__global__ __launch_bounds__(256)
void k_cvt_x(const float4* __restrict__ in, ushort4* __restrict__ out, int n4) {
  int i = blockIdx.x * 256 + threadIdx.x;
  if (i >= n4) return;
  float4 v = in[i];
  ushort4 o;
  o.x = f2bf(v.x); o.y = f2bf(v.y); o.z = f2bf(v.z); o.w = f2bf(v.w);
  out[i] = o;
}

// ---------------- K2: encoder [2048][16384] -> encT f32 [16384][2048] + encTb bf16 ----------------
__global__ __launch_bounds__(256)
void k_trans_enc(const float* __restrict__ enc,
                 float* __restrict__ encT,
                 unsigned short* __restrict__ encTb) {
  __shared__ float tile[32][33];
  const int c0 = blockIdx.x * 32;  // latent col base
  const int r0 = blockIdx.y * 32;  // input-dim row base
  const int tx = threadIdx.x, ty = threadIdx.y;
  #pragma unroll
  for (int i = ty; i < 32; i += 8)
    tile[i][tx] = enc[(size_t)(r0 + i) * LATDIM + c0 + tx];
  __syncthreads();
  #pragma unroll
  for (int i = ty; i < 32; i += 8) {
    float v = tile[tx][i];
    size_t o = (size_t)(c0 + i) * INDIM + r0 + tx;
    encT[o]  = v;
    encTb[o] = f2bf(v);
  }
}

// ---------------- K3: bf16 MFMA GEMM, 256x256 tile, 4-phase counted-vmcnt schedule ----------------
// 512 thr = 8 waves (2 Mx4 N), per-wave out 128x64. BK=64 split into two K=32 halves.
// LDS 128 KiB: A[2buf][2khalf][256r][32c] bf16 + B same. XOR swizzle bits[5:4]^=bits[8:7]
// (involution) applied to pre-swizzled global source (linear gload_lds dest) + ds_read addr.
// Issue schedule per tile t: P1:A-k1(t+1) P2:B-k1(t+1) P3:A-k0(t+2) P4:B-k0(t+2);
// single s_waitcnt vmcnt(4) at P4 guarantees everything through B-k1(t+1) landed.
#define KTILES 32

#define AREG(p, kh) (((p) * 2 + (kh)) * 16384)
#define BREG(p, kh) (65536 + ((p) * 2 + (kh)) * 16384)

#define MFMAQ(MQ)                                                             \
  {                                                                           \
    _Pragma("unroll") for (int mm = 0; mm < 4; ++mm) {                        \
      _Pragma("unroll") for (int nn = 0; nn < 4; ++nn) {                      \
        acc[(MQ)*4 + mm][nn] = __builtin_amdgcn_mfma_f32_16x16x32_bf16(       \
            a[(MQ)*4 + mm], b[nn], acc[(MQ)*4 + mm][nn], 0, 0, 0);            \
      }                                                                       \
    }                                                                         \
  }

__global__ __launch_bounds__(512, 2)
void k_gemm(const unsigned short* __restrict__ A,   // xb   [NROWS][INDIM] bf16 bits
            const unsigned short* __restrict__ BT,  // encTb[LATDIM][INDIM] bf16 bits
            float* __restrict__ C)                  // latent [NROWS][LATDIM] f32
{
  __shared__ __align__(16) char lds[131072];
  const int tid  = threadIdx.x;
  const int lane = tid & 63, wid = tid >> 6;
  const int wr = wid >> 2, wc = wid & 3;            // 2x4 waves

  // XCD-bijective swizzle: 2048 wgs = 8 XCDs x 256
  const int wg = ((blockIdx.x & 7) << 8) | ((int)blockIdx.x >> 3);
  const int bx = wg & 63, by = wg >> 6;             // 64 col-tiles, 32 row-tiles

  const unsigned short* aT = A  + (size_t)(by * 256) * INDIM;
  const unsigned short* bT = BT + (size_t)(bx * 256) * INDIM;

  // stage one K-half (256 rows x 32 cols bf16 = 16 KB): 2 gloads/wave, 8 waves
  auto stage = [&](const unsigned short* gRowBase, int col0, int region) {
    #pragma unroll
    for (int j = 0; j < 2; ++j) {
      const unsigned phys = (unsigned)((j * 8 + wid) * 1024 + lane * 16);
      const unsigned L = phys ^ (((phys >> 7) & 3u) << 4);  // involutive swizzle
      const unsigned row = L >> 6;
      const unsigned s = (L >> 4) & 3u;
      gload16(gRowBase + (size_t)row * INDIM + col0 + s * 8,
              lds + region + (j * 8 + wid) * 1024);
    }
  };

  bf16x8 a[8], b[4];
  auto rdA = [&](int p, int kk) {
    #pragma unroll
    for (int m = 0; m < 8; ++m) {
      const unsigned row = (unsigned)(wr * 128 + m * 16 + (lane & 15));
      const unsigned phys =
          (row * 64 + ((lane >> 4) << 4)) ^ (((row >> 1) & 3u) << 4);
      a[m] = *(const bf16x8*)(lds + AREG(p, kk) + phys);
    }
  };
  auto rdB = [&](int p, int kk) {
    #pragma unroll
    for (int n = 0; n < 4; ++n) {
      const unsigned row = (unsigned)(wc * 64 + n * 16 + (lane & 15));
      const unsigned phys =
          (row * 64 + ((lane >> 4) << 4)) ^ (((row >> 1) & 3u) << 4);
      b[n] = *(const bf16x8*)(lds + BREG(p, kk) + phys);
    }
  };

  const f32x4 fz = {0.f, 0.f, 0.f, 0.f};
  f32x4 acc[8][4];
  #pragma unroll
  for (int m = 0; m < 8; ++m)
    #pragma unroll
    for (int n = 0; n < 4; ++n) acc[m][n] = fz;

  // prologue: tile0 (4 halves) + tile1 k0 halves; complete tile0, keep 4 in flight
  stage(aT, 0,  AREG(0, 0)); stage(bT, 0,  BREG(0, 0));
  stage(aT, 32, AREG(0, 1)); stage(bT, 32, BREG(0, 1));
  stage(aT, 64, AREG(1, 0)); stage(bT, 64, BREG(1, 0));
  asm volatile("s_waitcnt vmcnt(4)" ::: "memory");
  __builtin_amdgcn_s_barrier();

  #pragma unroll 1
  for (int t = 0; t < KTILES; ++t) {
    const int p = t & 1;
    const int k1 = ((t + 1) & (KTILES - 1)) * 64;
    const int k2 = ((t + 2) & (KTILES - 1)) * 64;
    // ---- P1: read kk0 frags, prefetch A-k1(t+1), MFMA quad m0-3 kk0
    rdA(p, 0); rdB(p, 0);
    stage(aT, k1 + 32, AREG(p ^ 1, 1));
    __builtin_amdgcn_s_barrier();
    asm volatile("s_waitcnt lgkmcnt(0)" ::: "memory");
    __builtin_amdgcn_sched_barrier(0);
    __builtin_amdgcn_s_setprio(1);
    MFMAQ(0);
    __builtin_amdgcn_s_setprio(0);
    __builtin_amdgcn_s_barrier();
    // ---- P2: prefetch B-k1(t+1), MFMA quad m4-7 kk0
    stage(bT, k1 + 32, BREG(p ^ 1, 1));
    __builtin_amdgcn_s_barrier();
    __builtin_amdgcn_s_setprio(1);
    MFMAQ(1);
    __builtin_amdgcn_s_setprio(0);
    __builtin_amdgcn_s_barrier();
    // ---- P3: read kk1 frags, prefetch A-k0(t+2), MFMA quad m0-3 kk1
    rdA(p, 1); rdB(p, 1);
    stage(aT, k2, AREG(p, 0));
    __builtin_amdgcn_s_barrier();
    asm volatile("s_waitcnt lgkmcnt(0)" ::: "memory");
    __builtin_amdgcn_sched_barrier(0);
    __builtin_amdgcn_s_setprio(1);
    MFMAQ(0);
    __builtin_amdgcn_s_setprio(0);
    __builtin_amdgcn_s_barrier();
    // ---- P4: prefetch B-k0(t+2), counted wait, MFMA quad m4-7 kk1
    stage(bT, k2, BREG(p, 0));
    asm volatile("s_waitcnt vmcnt(4)" ::: "memory");
    __builtin_amdgcn_s_barrier();
    __builtin_amdgcn_s_setprio(1);
    MFMAQ(1);
    __builtin_amdgcn_s_setprio(0);
    __builtin_amdgcn_s_barrier();
  }
  asm volatile("s_waitcnt vmcnt(0)" ::: "memory");  // drain tail prefetches

  // C/D layout (m89-verified): col = lane&15, row = (lane>>4)*4 + reg
  const int r0  = by * 256 + wr * 128;
  const int c0g = bx * 256 + wc * 64;
  const int cr  = (lane >> 4) * 4;
  const int cc  = lane & 15;
  #pragma unroll
  for (int m = 0; m < 8; ++m)
    #pragma unroll
    for (int n = 0; n < 4; ++n)
      #pragma unroll
      for (int i = 0; i < 4; ++i)
        C[(size_t)(r0 + m * 16 + cr + i) * LATDIM + c0g + n * 16 + cc] =
            acc[m][n][i];
}

// ---------------- K4: exact top-32 via register-resident bisection ----------------
__global__ __launch_bounds__(256)
void k_topk(float* __restrict__ latent_sparse,   // d_out sparse region: latent in, sparse out
            const float* __restrict__ x,         // exact fp32 x
            const float* __restrict__ encT,      // exact fp32 encoder^T [LATDIM][INDIM]
            int* __restrict__ gIdx, float* __restrict__ gVal) {
  __shared__ int   redi[2][4];                   // per-wave counts, double-buffered
  __shared__ float redf[8];                      // min/max partials
  __shared__ int   selIdx[TOPK];
  __shared__ float selVal[TOPK];
  __shared__ int   candIdx[CAND_MAX];
  __shared__ float candApp[CAND_MAX];
  __shared__ float candEx[CAND_MAX];
  __shared__ unsigned char candUsed[CAND_MAX];
  __shared__ int nSel, nCand;

  const int tid = threadIdx.x;
  const int lane = tid & 63, wid = tid >> 6;
  const int row = blockIdx.x;
  float* lrow = latent_sparse + (size_t)row * LATDIM;

  // 1. stream row into registers: v[i] = lrow4[i*256 + tid]
  float4 v[16];
  {
    const float4* l4 = (const float4*)lrow;
    #pragma unroll
    for (int i = 0; i < 16; ++i) v[i] = l4[i * 256 + tid];
  }
  if (tid == 0) { nSel = 0; nCand = 0; }
  if (tid < TOPK) { selIdx[tid] = 0; selVal[tid] = 0.f; }

  // 2. block min/max
  float mx = -1e30f, mn = 1e30f;
  #pragma unroll
  for (int i = 0; i < 16; ++i) {
    mx = fmaxf(mx, fmaxf(fmaxf(v[i].x, v[i].y), fmaxf(v[i].z, v[i].w)));
    mn = fminf(mn, fminf(fminf(v[i].x, v[i].y), fminf(v[i].z, v[i].w)));
  }
  #pragma unroll
  for (int m2 = 32; m2 >= 1; m2 >>= 1) {
    mx = fmaxf(mx, __shfl_xor(mx, m2, 64));
    mn = fminf(mn, __shfl_xor(mn, m2, 64));
  }
  if (lane == 0) { redf[wid] = mx; redf[4 + wid] = mn; }
  __syncthreads();
  mx = fmaxf(fmaxf(redf[0], redf[1]), fmaxf(redf[2], redf[3]));
  mn = fminf(fminf(redf[4], redf[5]), fminf(redf[6], redf[7]));

  // 3. bisection: invariant cnt(>lo) >= 32, cnt(>hi) <= 32
  float lo = mn - 1.0f, hi = mx;
  for (int it = 0; it < BIS_ITERS; ++it) {
    const float mid = 0.5f * (lo + hi);
    int c = 0;
    #pragma unroll
    for (int i = 0; i < 16; ++i) {
      c += __popcll(__ballot(v[i].x > mid));
      c += __popcll(__ballot(v[i].y > mid));
      c += __popcll(__ballot(v[i].z > mid));
      c += __popcll(__ballot(v[i].w > mid));
    }
    if (lane == 0) redi[it & 1][wid] = c;
    __syncthreads();
    const int total = redi[it & 1][0] + redi[it & 1][1] + redi[it & 1][2] + redi[it & 1][3];
    if (total >= TOPK) lo = mid; else hi = mid;   // wave-uniform, all threads agree
  }

  // 4. classify: certain members and ambiguous candidates
  const float chi = hi + DELTA;
  const float clo = lo - DELTA;
  #pragma unroll
  for (int i = 0; i < 16; ++i) {
    #pragma unroll
    for (int j = 0; j < 4; ++j) {
      const float f = (j == 0) ? v[i].x : (j == 1) ? v[i].y : (j == 2) ? v[i].z : v[i].w;
      const int idx = i * 1024 + tid * 4 + j;
      if (f > chi) {
        int p = atomicAdd(&nSel, 1);
        if (p < TOPK) { selIdx[p] = idx; selVal[p] = f; }
      } else if (f > clo) {
        int p = atomicAdd(&nCand, 1);
        if (p < CAND_MAX) { candIdx[p] = idx; candApp[p] = f; }
      }
    }
  }
  __syncthreads();

  // 5. exact fp32 recompute of candidates (one wave per candidate)
  const int nc = min(nCand, CAND_MAX);
  const float* xr = x + (size_t)row * INDIM;
  for (int c = wid; c < nc; c += 4) {
    const float* er = encT + (size_t)candIdx[c] * INDIM;
    float acc = 0.f;
    for (int k = lane; k < INDIM; k += 64)
      acc = fmaf(xr[k], er[k], acc);
    #pragma unroll
    for (int m2 = 32; m2 >= 1; m2 >>= 1)
      acc += __shfl_xor(acc, m2, 64);
    if (lane == 0) candEx[c] = acc;
  }
  __syncthreads();

  // 6. resolve membership among candidates by exact value (ties -> lower index)
  if (tid == 0) {
    int ns = min(nSel, TOPK);
    int needF = TOPK - ns;
    for (int c = 0; c < nc; ++c) candUsed[c] = 0;
    int filled = 0;
    for (int t = 0; t < needF; ++t) {
      int best = -1;
      for (int c = 0; c < nc; ++c) {
        if (candUsed[c]) continue;
        if (best < 0 || candEx[c] > candEx[best] ||
            (candEx[c] == candEx[best] && candIdx[c] < candIdx[best]))
          best = c;
      }
      if (best < 0) break;
      candUsed[best] = 1;
      selIdx[ns + filled] = candIdx[best];
      selVal[ns + filled] = candApp[best];
      ++filled;
    }
  }
  __syncthreads();

  // 7. emit lists + rewrite the row in-place as sparse (zeros + 32 scatter)
  if (tid < TOPK) {
    gIdx[(size_t)row * TOPK + tid] = selIdx[tid];
    gVal[(size_t)row * TOPK + tid] = selVal[tid];
  }
  {
    const float4 z = {0.f, 0.f, 0.f, 0.f};
    float4* s4 = (float4*)lrow;
    #pragma unroll
    for (int i = 0; i < 16; ++i) s4[i * 256 + tid] = z;
  }
  __syncthreads();
  if (tid < TOPK) lrow[selIdx[tid]] = selVal[tid];
}

// ---------------- K5: decode (32 AXPYs of decoder rows per x-row) ----------------
__global__ __launch_bounds__(256)
void k_decode(const int* __restrict__ gIdx, const float* __restrict__ gVal,
              const float* __restrict__ dec, float* __restrict__ recon) {
  __shared__ int   sidx[TOPK];
  __shared__ float sval[TOPK];
  const int tid = threadIdx.x, row = blockIdx.x;
  if (tid < TOPK) {
    sidx[tid] = gIdx[(size_t)row * TOPK + tid];
    sval[tid] = gVal[(size_t)row * TOPK + tid];
  }
  __syncthreads();
  float4 a0 = {0.f,0.f,0.f,0.f}, a1 = {0.f,0.f,0.f,0.f};
  #pragma unroll 4
  for (int k = 0; k < TOPK; ++k) {
    const float v = sval[k];
    const float4* dr = (const float4*)(dec + (size_t)sidx[k] * HIDDIM);
    float4 d0 = dr[tid], d1 = dr[tid + 256];
    a0.x = fmaf(v, d0.x, a0.x); a0.y = fmaf(v, d0.y, a0.y);
    a0.z = fmaf(v, d0.z, a0.z); a0.w = fmaf(v, d0.w, a0.w);
    a1.x = fmaf(v, d1.x, a1.x); a1.y = fmaf(v, d1.y, a1.y);
    a1.z = fmaf(v, d1.z, a1.z); a1.w = fmaf(v, d1.w, a1.w);
  }
  float4* orow = (float4*)(recon + (size_t)row * HIDDIM);
  orow[tid] = a0; orow[tid + 256] = a1;
}

extern "C" void kernel_launch(void* const* d_in, const int* in_sizes, int n_in,
                              void* d_out, int out_size, void* d_ws, size_t ws_size,
                              hipStream_t stream) {
  (void)in_sizes; (void)n_in; (void)out_size; (void)ws_size;
  const float* x   = (const float*)d_in[0];   // [8192][2048]
  const float* enc = (const float*)d_in[1];   // [2048][16384]
  const float* dec = (const float*)d_in[2];   // [16384][2048]

  float* recon  = (float*)d_out;                        // [8192][2048]
  float* sparse = recon + (size_t)NROWS * HIDDIM;       // [8192][16384] (also latent scratch)

  // ws layout (~226 MB needed)
  char* w = (char*)d_ws;
  unsigned short* xb    = (unsigned short*)w;                             // 32 MB
  unsigned short* encTb = (unsigned short*)(w + (size_t)33554432);        // 64 MB
  float*          encT  = (float*)(w + (size_t)100663296);                // 128 MB
  int*            gIdx  = (int*)(w + (size_t)234881024);                  // 1 MB
  float*          gVal  = (float*)(w + (size_t)235929600);                // 1 MB

  k_cvt_x<<<(NROWS * INDIM / 4 + 255) / 256, 256, 0, stream>>>(
      (const float4*)x, (ushort4*)xb, NROWS * INDIM / 4);
  k_trans_enc<<<dim3(LATDIM / 32, INDIM / 32), dim3(32, 8), 0, stream>>>(enc, encT, encTb);
  k_gemm<<<dim3((NROWS / 256) * (LATDIM / 256)), 512, 0, stream>>>(xb, encTb, sparse);
  k_topk<<<NROWS, 256, 0, stream>>>(sparse, x, encT, gIdx, gVal);
  k_decode<<<NROWS, 256, 0, stream>>>(gIdx, gVal, dec, recon);
}